// Round 1
// baseline (1856.870 us; speedup 1.0000x reference)
//
#include <hip/hip_runtime.h>
#include <cstdint>

// ---------------------------------------------------------------------------
// WindowAttention on MI355X, bf16 MFMA pipeline.
// Workspace layout (needs ~520 MB):
//   xw   : bf16 [65536][1024]  windowed x (reused as attention-out later)
//   qkvb : bf16 [3][256][16][256][64]   q/k/v per (s, win, head, t, d)
//   wq   : bf16 [3072][1024]
//   wp   : bf16 [1024][1024]
// ---------------------------------------------------------------------------

typedef __bf16 bfx8 __attribute__((ext_vector_type(8)));
typedef float  fx4  __attribute__((ext_vector_type(4)));

__device__ __forceinline__ unsigned short f2bf(float f) {
  union { float f; unsigned u; } v; v.f = f;
  return (unsigned short)((v.u + 0x7FFFu + ((v.u >> 16) & 1u)) >> 16);
}

__device__ __forceinline__ void load_lds16(const void* g, void* l) {
  __builtin_amdgcn_global_load_lds((const __attribute__((address_space(1))) void*)g,
                                   (__attribute__((address_space(3))) void*)l,
                                   16, 0, 0);
}

// --------------------------- f32 -> bf16 cast ------------------------------
__global__ void cvt_bf16(const float* __restrict__ in, unsigned short* __restrict__ out, int n) {
  int i = (blockIdx.x * 256 + threadIdx.x) * 8;
  if (i >= n) return;
  float4 v0 = ((const float4*)(in + i))[0];
  float4 v1 = ((const float4*)(in + i))[1];
  union { unsigned short s[8]; uint4 q; } o;
  o.s[0] = f2bf(v0.x); o.s[1] = f2bf(v0.y); o.s[2] = f2bf(v0.z); o.s[3] = f2bf(v0.w);
  o.s[4] = f2bf(v1.x); o.s[5] = f2bf(v1.y); o.s[6] = f2bf(v1.z); o.s[7] = f2bf(v1.w);
  *(uint4*)(out + i) = o.q;
}

// ------------------- pack x into windowed order, bf16 ----------------------
// m = ((b*8 + wh)*8 + ww)*256 + r*16 + c  ->  x[b][ (wh*16+r)*128 + ww*16+c ][:]
__global__ void pack_x_win(const float* __restrict__ x, unsigned short* __restrict__ xw) {
  int64_t idx = (int64_t)blockIdx.x * 256 + threadIdx.x;   // 8M threads
  int m = (int)(idx >> 7);
  int c = ((int)idx & 127) << 3;
  int win = m >> 8, t = m & 255;
  int b = win >> 6, wh = (win >> 3) & 7, ww = win & 7;
  int n = ((wh << 4) + (t >> 4)) * 128 + (ww << 4) + (t & 15);
  const float* src = x + (((int64_t)b * 16384 + n) << 10) + c;
  float4 v0 = ((const float4*)src)[0];
  float4 v1 = ((const float4*)src)[1];
  union { unsigned short s[8]; uint4 q; } o;
  o.s[0] = f2bf(v0.x); o.s[1] = f2bf(v0.y); o.s[2] = f2bf(v0.z); o.s[3] = f2bf(v0.w);
  o.s[4] = f2bf(v1.x); o.s[5] = f2bf(v1.y); o.s[6] = f2bf(v1.z); o.s[7] = f2bf(v1.w);
  *(uint4*)(xw + ((int64_t)m << 10) + c) = o.q;
}

// --------------------- 128x128-tile bf16 GEMM (B^T) ------------------------
// C[m][n] = sum_k A[m][k] * B[n][k], K = 1024 fixed.
// EPI 0: qkv epilogue (RoPE on q,k; write bf16 [s][win][h][t][d])
// EPI 1: proj epilogue (un-window; write fp32 to d_out)
template<int EPI>
__global__ __launch_bounds__(256) void gemm_bt(
    const unsigned short* __restrict__ A,
    const unsigned short* __restrict__ B,
    unsigned short* __restrict__ qkvb,
    float* __restrict__ outp)
{
  __shared__ unsigned short Als[128 * 32];
  __shared__ unsigned short Bls[128 * 32];
  const int tid  = threadIdx.x;
  const int wave = tid >> 6;
  const int lane = tid & 63;
  const int lr = lane & 15, lg = lane >> 4;
  const int tileN = blockIdx.x * 128;
  const int tileM = blockIdx.y * 128;
  const int wm = (wave >> 1) * 64, wn = (wave & 1) * 64;

  // staging: 8 segments of 16 rows x 32 cols; wave w does segments 2w, 2w+1
  const int seg = wave * 2;
  const int rs = lane >> 2;
  const int cs = (lane & 3) * 8;
  const unsigned short* Ag0 = A + (int64_t)(tileM + seg * 16      + rs) * 1024 + cs;
  const unsigned short* Ag1 = A + (int64_t)(tileM + seg * 16 + 16 + rs) * 1024 + cs;
  const unsigned short* Bg0 = B + (int64_t)(tileN + seg * 16      + rs) * 1024 + cs;
  const unsigned short* Bg1 = B + (int64_t)(tileN + seg * 16 + 16 + rs) * 1024 + cs;
  unsigned short* lA0 = &Als[seg * 512];
  unsigned short* lA1 = &Als[seg * 512 + 512];
  unsigned short* lB0 = &Bls[seg * 512];
  unsigned short* lB1 = &Bls[seg * 512 + 512];

  fx4 acc[4][4];
#pragma unroll
  for (int i = 0; i < 4; i++)
#pragma unroll
    for (int j = 0; j < 4; j++) acc[i][j] = {0.f, 0.f, 0.f, 0.f};

  for (int k0 = 0; k0 < 1024; k0 += 32) {
    __syncthreads();
    load_lds16(Ag0 + k0, lA0);
    load_lds16(Ag1 + k0, lA1);
    load_lds16(Bg0 + k0, lB0);
    load_lds16(Bg1 + k0, lB1);
    __syncthreads();
    bfx8 af[4], bfr[4];
#pragma unroll
    for (int mi = 0; mi < 4; mi++) af[mi]  = *(const bfx8*)&Als[(wm + mi * 16 + lr) * 32 + lg * 8];
#pragma unroll
    for (int ni = 0; ni < 4; ni++) bfr[ni] = *(const bfx8*)&Bls[(wn + ni * 16 + lr) * 32 + lg * 8];
#pragma unroll
    for (int mi = 0; mi < 4; mi++)
#pragma unroll
      for (int ni = 0; ni < 4; ni++)
        acc[mi][ni] = __builtin_amdgcn_mfma_f32_16x16x32_bf16(af[mi], bfr[ni], acc[mi][ni], 0, 0, 0);
  }

  if (EPI == 0) {
    // C/D layout: col = lane&15 (f), row = lg*4 + r (m). Adjacent d in adjacent lanes.
#pragma unroll
    for (int ni = 0; ni < 4; ni++) {
      const int f = tileN + wn + ni * 16 + lr;
      const int s = f >> 10;              // uniform within block
      const int h = (f >> 6) & 15;        // uniform within 16-col tile
      const int d = f & 63;
      const int p = d >> 1;
      const bool rope = (s < 2);
      const float invf = __powf(10000.0f, -(float)p * (1.0f / 32.0f));
#pragma unroll
      for (int mi = 0; mi < 4; mi++) {
        const int m0 = tileM + wm + mi * 16 + lg * 4;
#pragma unroll
        for (int r = 0; r < 4; r++) {
          const int m = m0 + r;
          const int win = m >> 8, t = m & 255;
          float v = acc[mi][ni][r];
          float pv = __shfl_xor(v, 1);    // pair partner (d^1), same row
          float o = v;
          if (rope) {
            const int pos = (p < 16) ? (t >> 4) : (t & 15);
            float fr = (float)pos * invf;
            float sn, cn;
            __sincosf(fr, &sn, &cn);
            o = (d & 1) ? (v * cn + pv * sn) : (v * cn - pv * sn);
          }
          qkvb[((((int64_t)s * 256 + win) * 16 + h) * 256 + t) * 64 + d] = f2bf(o);
        }
      }
    }
  } else {
#pragma unroll
    for (int mi = 0; mi < 4; mi++) {
      const int m0 = tileM + wm + mi * 16 + lg * 4;
#pragma unroll
      for (int r = 0; r < 4; r++) {
        const int m = m0 + r;
        const int win = m >> 8, t = m & 255;
        const int b = win >> 6, wh = (win >> 3) & 7, ww = win & 7;
        const int n = ((wh << 4) + (t >> 4)) * 128 + (ww << 4) + (t & 15);
        float* dst = outp + (((int64_t)b * 16384 + n) << 10) + tileN + wn;
#pragma unroll
        for (int ni = 0; ni < 4; ni++) dst[ni * 16 + lr] = acc[mi][ni][r];
      }
    }
  }
}

// ----------------------- windowed flash attention --------------------------
// 1 block per (win, head); 4 waves, wave w owns q rows [64w, 64w+64).
__global__ __launch_bounds__(256) void win_attn(
    const unsigned short* __restrict__ qkvb,
    unsigned short* __restrict__ aout)
{
  __shared__ unsigned short VT[64 * 264];       // V^T, padded stride 264
  __shared__ unsigned short Pl[4][64 * 32];     // per-wave P staging
  const int bx = blockIdx.x;
  const int win = bx >> 4, h = bx & 15;
  const int tid = threadIdx.x, wave = tid >> 6, lane = tid & 63;
  const int lr = lane & 15, lg = lane >> 4;

  const unsigned short* qp = qkvb + (((int64_t)(      win) * 16 + h) << 14);
  const unsigned short* kp = qkvb + (((int64_t)(256 + win) * 16 + h) << 14);
  const unsigned short* vp = qkvb + (((int64_t)(512 + win) * 16 + h) << 14);

  // stage V^T into LDS
  for (int i = tid; i < 2048; i += 256) {
    int t = i >> 3, dg = (i & 7) * 8;
    union { uint4 q; unsigned short s[8]; } v;
    v.q = *(const uint4*)(vp + t * 64 + dg);
#pragma unroll
    for (int j = 0; j < 8; j++) VT[(dg + j) * 264 + t] = v.s[j];
  }

  // Q fragments, resident across the whole K sweep
  bfx8 qf[4][2];
#pragma unroll
  for (int mi = 0; mi < 4; mi++)
#pragma unroll
    for (int ks = 0; ks < 2; ks++)
      qf[mi][ks] = *(const bfx8*)(qp + (wave * 64 + mi * 16 + lr) * 64 + ks * 32 + lg * 8);

  fx4 o[4][4];
#pragma unroll
  for (int i = 0; i < 4; i++)
#pragma unroll
    for (int j = 0; j < 4; j++) o[i][j] = {0.f, 0.f, 0.f, 0.f};
  float mrow[4][4], lrow[4][4];
#pragma unroll
  for (int i = 0; i < 4; i++)
#pragma unroll
    for (int r = 0; r < 4; r++) { mrow[i][r] = -INFINITY; lrow[i][r] = 0.f; }

  __syncthreads();

  for (int kc = 0; kc < 8; kc++) {              // 32 k-tokens per chunk
    bfx8 kf[2][2];
#pragma unroll
    for (int nt = 0; nt < 2; nt++)
#pragma unroll
      for (int ks = 0; ks < 2; ks++)
        kf[nt][ks] = *(const bfx8*)(kp + (kc * 32 + nt * 16 + lr) * 64 + ks * 32 + lg * 8);

    fx4 sa[4][2];
#pragma unroll
    for (int mi = 0; mi < 4; mi++)
#pragma unroll
      for (int nt = 0; nt < 2; nt++) sa[mi][nt] = {0.f, 0.f, 0.f, 0.f};
#pragma unroll
    for (int mi = 0; mi < 4; mi++)
#pragma unroll
      for (int nt = 0; nt < 2; nt++) {
        sa[mi][nt] = __builtin_amdgcn_mfma_f32_16x16x32_bf16(qf[mi][0], kf[nt][0], sa[mi][nt], 0, 0, 0);
        sa[mi][nt] = __builtin_amdgcn_mfma_f32_16x16x32_bf16(qf[mi][1], kf[nt][1], sa[mi][nt], 0, 0, 0);
      }

    // online softmax, rows = lg*4 + r per 16-lane group
#pragma unroll
    for (int mi = 0; mi < 4; mi++) {
#pragma unroll
      for (int r = 0; r < 4; r++) {
        float s0 = sa[mi][0][r] * 0.125f, s1 = sa[mi][1][r] * 0.125f;
        float mx = fmaxf(s0, s1);
        mx = fmaxf(mx, __shfl_xor(mx, 1));
        mx = fmaxf(mx, __shfl_xor(mx, 2));
        mx = fmaxf(mx, __shfl_xor(mx, 4));
        mx = fmaxf(mx, __shfl_xor(mx, 8));
        float mold = mrow[mi][r];
        float mnew = fmaxf(mold, mx);
        float alpha = __expf(mold - mnew);
        float p0 = __expf(s0 - mnew), p1 = __expf(s1 - mnew);
        float ps = p0 + p1;
        ps += __shfl_xor(ps, 1);
        ps += __shfl_xor(ps, 2);
        ps += __shfl_xor(ps, 4);
        ps += __shfl_xor(ps, 8);
        lrow[mi][r] = lrow[mi][r] * alpha + ps;
        mrow[mi][r] = mnew;
#pragma unroll
        for (int ni = 0; ni < 4; ni++) o[mi][ni][r] *= alpha;
        const int prow = mi * 16 + lg * 4 + r;
        Pl[wave][prow * 32 +      lr] = f2bf(p0);
        Pl[wave][prow * 32 + 16 + lr] = f2bf(p1);
      }
    }

    // P @ V chunk
    bfx8 pa[4], vb[4];
#pragma unroll
    for (int mi = 0; mi < 4; mi++) pa[mi] = *(const bfx8*)&Pl[wave][(mi * 16 + lr) * 32 + lg * 8];
#pragma unroll
    for (int ni = 0; ni < 4; ni++) vb[ni] = *(const bfx8*)&VT[(ni * 16 + lr) * 264 + kc * 32 + lg * 8];
#pragma unroll
    for (int mi = 0; mi < 4; mi++)
#pragma unroll
      for (int ni = 0; ni < 4; ni++)
        o[mi][ni] = __builtin_amdgcn_mfma_f32_16x16x32_bf16(pa[mi], vb[ni], o[mi][ni], 0, 0, 0);
  }

  // normalize + store bf16 [win*256+t][h*64+d]
#pragma unroll
  for (int mi = 0; mi < 4; mi++)
#pragma unroll
    for (int r = 0; r < 4; r++) {
      const int t = wave * 64 + mi * 16 + lg * 4 + r;
      const float inv = 1.0f / lrow[mi][r];
      unsigned short* dst = aout + ((int64_t)(win * 256 + t) << 10) + h * 64;
#pragma unroll
      for (int ni = 0; ni < 4; ni++) dst[ni * 16 + lr] = f2bf(o[mi][ni][r] * inv);
    }
}

// ---------------------------------------------------------------------------
extern "C" void kernel_launch(void* const* d_in, const int* in_sizes, int n_in,
                              void* d_out, int out_size, void* d_ws, size_t ws_size,
                              hipStream_t stream) {
  const float* x     = (const float*)d_in[0];
  // d_in[1] = position_ids (unused by the reference math; RoPE is window-local)
  const float* Wqkv  = (const float*)d_in[2];
  const float* Wproj = (const float*)d_in[3];
  float* out = (float*)d_out;

  uint8_t* ws = (uint8_t*)d_ws;
  unsigned short* xw   = (unsigned short*)(ws);                     // 134217728 B
  unsigned short* qkvb = (unsigned short*)(ws + 134217728ll);       // 402653184 B
  unsigned short* wq   = (unsigned short*)(ws + 536870912ll);       //   6291456 B
  unsigned short* wp   = (unsigned short*)(ws + 543162368ll);       //   2097152 B

  cvt_bf16<<<1536, 256, 0, stream>>>(Wqkv, wq, 3072 * 1024);
  cvt_bf16<<<512, 256, 0, stream>>>(Wproj, wp, 1024 * 1024);
  pack_x_win<<<32768, 256, 0, stream>>>(x, xw);

  gemm_bt<0><<<dim3(24, 512), 256, 0, stream>>>(xw, wq, qkvb, nullptr);
  win_attn<<<4096, 256, 0, stream>>>(qkvb, xw);   // xw reused as attn-out
  gemm_bt<1><<<dim3(8, 512), 256, 0, stream>>>(xw, wp, nullptr, out);
}